// Round 11
// baseline (496.633 us; speedup 1.0000x reference)
//
#include <hip/hip_runtime.h>
#include <hip/hip_fp16.h>
#include <stdint.h>

typedef int i32x4 __attribute__((ext_vector_type(4)));

#define BM 256
#define BN 256
#define BKB 128           // K-bytes (= int8 elems) per tile
#define ASLOT 32768       // A slot: 256 rows x 128 B; 2 slots = 64 KB LDS
#define THREADS 512

__device__ __forceinline__ void gload_lds16(const void* g, void* l) {
  __builtin_amdgcn_global_load_lds(
      (const __attribute__((address_space(1))) unsigned int*)g,
      (__attribute__((address_space(3))) unsigned int*)l, 16, 0, 0);
}

// ---------------- quantize x: fp32(fp16 values) -> int8, grid-stride --------
__global__ __launch_bounds__(256) void quant_x_kernel(
    const float* __restrict__ x, const float* __restrict__ deltap,
    const float* __restrict__ zpp, int8_t* __restrict__ q, int n16) {
  const float rdelta = 1.0f / deltap[0];
  const float zp = zpp[0];
  for (int i = blockIdx.x * blockDim.x + threadIdx.x; i < n16;
       i += gridDim.x * blockDim.x) {
    const float4* src = (const float4*)x + (size_t)i * 4;
    int packed[4];
#pragma unroll
    for (int g = 0; g < 4; ++g) {
      float4 v = src[g];
      float f0 = fminf(127.f, fmaxf(-128.f, rintf(fmaf(v.x, rdelta, zp))));
      float f1 = fminf(127.f, fmaxf(-128.f, rintf(fmaf(v.y, rdelta, zp))));
      float f2 = fminf(127.f, fmaxf(-128.f, rintf(fmaf(v.z, rdelta, zp))));
      float f3 = fminf(127.f, fmaxf(-128.f, rintf(fmaf(v.w, rdelta, zp))));
      int q0 = (int)f0 & 255, q1 = (int)f1 & 255, q2 = (int)f2 & 255, q3 = (int)f3 & 255;
      packed[g] = q0 | (q1 << 8) | (q2 << 16) | (q3 << 24);
    }
    ((int4*)q)[i] = make_int4(packed[0], packed[1], packed[2], packed[3]);
  }
}

// ---------------- pack W: int32 -> int8, 16 elems/thread --------------------
__global__ __launch_bounds__(256) void pack_w_kernel(
    const int* __restrict__ w, int8_t* __restrict__ wp, int n16) {
  int i = blockIdx.x * blockDim.x + threadIdx.x;
  if (i >= n16) return;
  const int4* src = (const int4*)w + (size_t)i * 4;
  int packed[4];
#pragma unroll
  for (int g = 0; g < 4; ++g) {
    int4 v = src[g];
    packed[g] = (v.x & 255) | ((v.y & 255) << 8) | ((v.z & 255) << 16) | ((v.w & 255) << 24);
  }
  ((int4*)wp)[i] = make_int4(packed[0], packed[1], packed[2], packed[3]);
}

// ---------------- int8 GEMM: A staged in LDS, B direct from L2 --------------
// W' is 4 MB (L2-resident): B fragments load global->VGPR on the async vmem
// pipe (issued at tile top, drain under the MFMA window) -> LDS pipe carries
// only A (reads 128 KB + writes 32 KB per CU-tile vs r8's 320 KB), and the
// DMA per tile halves to 32 KB. Serial wave chain ~4100 cy vs r8's 6450.
// 8 waves (2M x 4N), wave-tile 128x64, acc[8][4] i32x4 (128 VGPR) + B ping-
// pong 2x32 + A per-ks 32 -> ~240 VGPR at 2 waves/SIMD.
// A chunk-XOR swizzle (r8-verified): LDS[r][c] = G[r][c ^ (r&7)].
__global__ __launch_bounds__(THREADS, 2) void gemm_i8_kernel(
    const int8_t* __restrict__ Aq, const int8_t* __restrict__ Bw,
    const float* __restrict__ atwd, const float* __restrict__ zpws,
    const float* __restrict__ bias, float* __restrict__ out,
    int Mc, int Nc, int Kc) {
  __shared__ int8_t lds[2 * ASLOT];

  // ---- T1 bijective XCD swizzle (nwg multiple of 8 here) ----
  const int nwg = gridDim.x;
  int bid = blockIdx.x;
  if ((nwg & 7) == 0) bid = (bid & 7) * (nwg >> 3) + (bid >> 3);
  const int nbn = Nc / BN;
  const int bm = bid / nbn;
  const int bn = bid % nbn;

  const int tid = threadIdx.x;
  const size_t K = (size_t)Kc;
  const int NT = Kc / BKB;

  // ---- A staging: sweep = 512 thr x 16B = 8KB = 64 rows x 128B, 4 sweeps ---
  const int srow = tid >> 3;                        // 0..63
  const int cs = tid & 7;                           // storage chunk
  const int cl = cs ^ (srow & 7);                   // inverse-swizzled source
  const int8_t* gA = Aq + ((size_t)(bm * BM + srow)) * K + cl * 16;
  const size_t row64 = (size_t)64 * K;
  int8_t* ldst = &lds[tid * 16];

  auto stageA = [&](int t, int slot) {   // 4 gloads: A 4 x 8KB
    int8_t* l = ldst + slot * ASLOT;
    const size_t koff = (size_t)t * BKB;
#pragma unroll
    for (int r = 0; r < 4; ++r)
      gload_lds16(gA + koff + r * row64, l + r * 8192);
  };

  // ---- fragment geometry: 8 waves 2x4, wave-tile 128x64 ----
  const int lane = tid & 63;
  const int wave = tid >> 6;
  const int wr = wave >> 2;          // 0..1 -> 128-row halves
  const int wc = wave & 3;           // 0..3 -> 64-col strips
  const int fr = lane & 15;
  const int kc = lane >> 4;          // 16B chunk within 64B K-step
  const int swz = fr & 7;
  const int aRow = wr * 128 + fr;

  // ---- B direct-load base: lane (fr,kc) reads W'[bn*BN+wc*64+j*16+fr][...]
  const int8_t* gB = Bw + ((size_t)(bn * BN + wc * 64 + fr)) * K + kc * 16;

  i32x4 acc[8][4] = {};
  i32x4 bfA[4][2], bfB[4][2];

#define LOADB(REG, t)                                                         \
  _Pragma("unroll") for (int j_ = 0; j_ < 4; ++j_)                            \
    _Pragma("unroll") for (int ks_ = 0; ks_ < 2; ++ks_)                       \
      REG[j_][ks_] = *(const i32x4*)&gB[(size_t)(j_ * 16) * K +               \
                                        (size_t)(t) * BKB + ks_ * 64];

#define TILE(t, CUR, NXT)                                                     \
  {                                                                           \
    const int8_t* sA_ = &lds[((t) & 1) * ASLOT];                              \
    if ((t) + 1 < NT) { LOADB(NXT, (t) + 1); stageA((t) + 1, ((t) + 1) & 1); }\
    _Pragma("unroll") for (int ks_ = 0; ks_ < 2; ++ks_) {                     \
      const int co_ = ((ks_ * 4 + kc) ^ swz) << 4;                            \
      i32x4 af_[8];                                                           \
      _Pragma("unroll") for (int i_ = 0; i_ < 8; ++i_)                        \
        af_[i_] = *(const i32x4*)&sA_[(aRow + ((i_ & 3) * 16) +               \
                                      ((i_ >> 2) * 64)) * 128 + co_];         \
      _Pragma("unroll") for (int i_ = 0; i_ < 8; ++i_)                        \
        _Pragma("unroll") for (int j_ = 0; j_ < 4; ++j_)                      \
          acc[i_][j_] = __builtin_amdgcn_mfma_i32_16x16x64_i8(                \
              af_[i_], CUR[j_][ks_], acc[i_][j_], 0, 0, 0);                   \
    }                                                                         \
    if ((t) < NT - 1) {                                                       \
      asm volatile("s_waitcnt vmcnt(0)" ::: "memory");                        \
      __builtin_amdgcn_s_barrier();                                           \
      __builtin_amdgcn_sched_barrier(0);                                      \
    }                                                                         \
  }

  // ---- prologue: stage A(0), load B(0); drain; barrier ----
  stageA(0, 0);
  LOADB(bfA, 0);
  asm volatile("s_waitcnt vmcnt(0)" ::: "memory");
  __builtin_amdgcn_s_barrier();
  __builtin_amdgcn_sched_barrier(0);

  for (int t = 0; t < NT; t += 2) {
    TILE(t, bfA, bfB);
    TILE(t + 1, bfB, bfA);
  }
#undef TILE
#undef LOADB

  // ---- epilogue (r8-verified): C/D col=lane&15, row=(lane>>4)*4+reg;
  // j innermost, mrow = (i&3)*16 + (i>>2)*64.
  const int r4 = (lane >> 4) << 2;
  const int cn0 = bn * BN + wc * 64 + fr;
  float aw4[4], zs4[4], bs4[4];
#pragma unroll
  for (int j = 0; j < 4; ++j) {
    aw4[j] = atwd[cn0 + j * 16];
    zs4[j] = zpws[cn0 + j * 16];
    bs4[j] = bias[cn0 + j * 16];
  }
#pragma unroll
  for (int i = 0; i < 8; ++i) {
    const int mrow = ((i & 3) * 16) + ((i >> 2) * 64);
#pragma unroll
    for (int r = 0; r < 4; ++r) {
      const size_t rbase = (size_t)(bm * BM + wr * 128 + mrow + r4 + r) * (size_t)Nc;
#pragma unroll
      for (int j = 0; j < 4; ++j) {
        float v = (float)acc[i][j][r] * aw4[j] - zs4[j] + bs4[j];
        v = __half2float(__float2half(v));  // match fp16 output rounding
        out[rbase + cn0 + j * 16] = v;
      }
    }
  }
}

extern "C" void kernel_launch(void* const* d_in, const int* in_sizes, int n_in,
                              void* d_out, int out_size, void* d_ws, size_t ws_size,
                              hipStream_t stream) {
  const float* x         = (const float*)d_in[0];
  const float* act_delta = (const float*)d_in[1];
  const float* act_zp    = (const float*)d_in[2];
  const float* zpws      = (const float*)d_in[3];
  const float* atwd      = (const float*)d_in[4];
  const float* bias      = (const float*)d_in[5];
  const int*   w32       = (const int*)d_in[6];
  float* out = (float*)d_out;

  const int N = in_sizes[5];
  const int K = in_sizes[6] / N;
  const int M = in_sizes[0] / K;

  int8_t* q  = (int8_t*)d_ws;               // M*K bytes
  int8_t* wp = q + (size_t)M * K;           // N*K bytes

  {
    int n16 = (M * K) / 16;
    int grid = (n16 + 255) / 256;
    if (grid > 2048) grid = 2048;
    quant_x_kernel<<<grid, 256, 0, stream>>>(x, act_delta, act_zp, q, n16);
  }
  {
    int n16 = (N * K) / 16;
    pack_w_kernel<<<(n16 + 255) / 256, 256, 0, stream>>>(w32, wp, n16);
  }
  {
    dim3 grid((M / BM) * (N / BN));
    gemm_i8_kernel<<<grid, THREADS, 0, stream>>>(q, wp, atwd, zpws, bias, out, M, N, K);
  }
}

// Round 12
// 259.202 us; speedup vs baseline: 1.9160x; 1.9160x over previous
//
#include <hip/hip_runtime.h>
#include <hip/hip_fp16.h>
#include <stdint.h>

typedef int i32x4 __attribute__((ext_vector_type(4)));

#define BM 256
#define BN 256
#define BKB 64            // K-bytes (= int8 elems) per tile
#define NSLOT 4
#define SLOT_BYTES 32768  // A 16KB + B 16KB per slot
#define THREADS 512

__device__ __forceinline__ void gload_lds16(const void* g, void* l) {
  __builtin_amdgcn_global_load_lds(
      (const __attribute__((address_space(1))) unsigned int*)g,
      (__attribute__((address_space(3))) unsigned int*)l, 16, 0, 0);
}

// ---------------- quantize x: fp32(fp16 values) -> int8, grid-stride --------
__global__ __launch_bounds__(256) void quant_x_kernel(
    const float* __restrict__ x, const float* __restrict__ deltap,
    const float* __restrict__ zpp, int8_t* __restrict__ q, int n16) {
  const float rdelta = 1.0f / deltap[0];
  const float zp = zpp[0];
  for (int i = blockIdx.x * blockDim.x + threadIdx.x; i < n16;
       i += gridDim.x * blockDim.x) {
    const float4* src = (const float4*)x + (size_t)i * 4;
    int packed[4];
#pragma unroll
    for (int g = 0; g < 4; ++g) {
      float4 v = src[g];
      float f0 = fminf(127.f, fmaxf(-128.f, rintf(fmaf(v.x, rdelta, zp))));
      float f1 = fminf(127.f, fmaxf(-128.f, rintf(fmaf(v.y, rdelta, zp))));
      float f2 = fminf(127.f, fmaxf(-128.f, rintf(fmaf(v.z, rdelta, zp))));
      float f3 = fminf(127.f, fmaxf(-128.f, rintf(fmaf(v.w, rdelta, zp))));
      int q0 = (int)f0 & 255, q1 = (int)f1 & 255, q2 = (int)f2 & 255, q3 = (int)f3 & 255;
      packed[g] = q0 | (q1 << 8) | (q2 << 16) | (q3 << 24);
    }
    ((int4*)q)[i] = make_int4(packed[0], packed[1], packed[2], packed[3]);
  }
}

// ---------------- pack W: int32 -> int8, 16 elems/thread --------------------
__global__ __launch_bounds__(256) void pack_w_kernel(
    const int* __restrict__ w, int8_t* __restrict__ wp, int n16) {
  int i = blockIdx.x * blockDim.x + threadIdx.x;
  if (i >= n16) return;
  const int4* src = (const int4*)w + (size_t)i * 4;
  int packed[4];
#pragma unroll
  for (int g = 0; g < 4; ++g) {
    int4 v = src[g];
    packed[g] = (v.x & 255) | ((v.y & 255) << 8) | ((v.z & 255) << 16) | ((v.w & 255) << 24);
  }
  ((int4*)wp)[i] = make_int4(packed[0], packed[1], packed[2], packed[3]);
}

// ---------------- int8 GEMM, 256x256 tile, fine-phase interleave ------------
// r4 frame unchanged (4-slot rotation, depth-3, counted vmcnt(8), chunk-XOR
// swizzle 0-conflicts, XCD swizzle, 8 waves 2Mx4N wave-tile 128x64).
// NEW: interior split into 2 m201-style phases per tile so LDS-port work
// arrives in small batches that hide under 650cy/SIMD MFMA clusters instead
// of one lockstep read-block (which made pipes SUM -> 6450cy walls):
//   ph0: {8 ds_read | stage(t+3)} bar lgkm(0) prio1 16xMFMA prio0 bar
//   ph1: {4 ds_read}              bar lgkm(0) prio1 16xMFMA prio0 vmcnt bar
__global__ __launch_bounds__(THREADS, 2) void gemm_i8_kernel(
    const int8_t* __restrict__ Aq, const int8_t* __restrict__ Bw,
    const float* __restrict__ atwd, const float* __restrict__ zpws,
    const float* __restrict__ bias, float* __restrict__ out,
    int Mc, int Nc, int Kc) {
  __shared__ int8_t lds[NSLOT * SLOT_BYTES];

  // ---- T1 bijective XCD swizzle (nwg multiple of 8 here) ----
  const int nwg = gridDim.x;
  int bid = blockIdx.x;
  if ((nwg & 7) == 0) bid = (bid & 7) * (nwg >> 3) + (bid >> 3);
  const int nbn = Nc / BN;
  const int bm = bid / nbn;
  const int bn = bid % nbn;

  const int tid = threadIdx.x;
  const size_t K = (size_t)Kc;
  const int NT = Kc / BKB;

  // ---- staging: sweep = 512 thr x 16B = 8KB = 128 rows x 64B ----
  const int srow = tid >> 2;                        // 0..127
  const int lc = (tid & 3) ^ ((tid >> 3) & 3);      // inverse-swizzled chunk
  const int8_t* gA = Aq + ((size_t)(bm * BM + srow)) * K + lc * 16;
  const int8_t* gB = Bw + ((size_t)(bn * BN + srow)) * K + lc * 16;
  const size_t half_off = (size_t)128 * K;
  int8_t* ldst = &lds[tid * 16];

  auto stageA = [&](int t) {
    int8_t* l = ldst + (t & 3) * SLOT_BYTES;
    gload_lds16(gA + (size_t)t * BKB, l);
    gload_lds16(gA + (size_t)t * BKB + half_off, l + 8192);
  };
  auto stageB = [&](int t) {
    int8_t* l = ldst + (t & 3) * SLOT_BYTES + 16384;
    gload_lds16(gB + (size_t)t * BKB, l);
    gload_lds16(gB + (size_t)t * BKB + half_off, l + 8192);
  };

  // ---- fragment geometry ----
  const int lane = tid & 63;
  const int wave = tid >> 6;
  const int wr = wave >> 2;          // 0..1 -> 128-row halves
  const int wc = wave & 3;           // 0..3 -> 64-col strips
  const int fr = lane & 15;
  const int kc = lane >> 4;
  const int coff = ((kc ^ ((fr >> 1) & 3)) << 4);  // swizzled ds_read chunk
  const int aRow = wr * 128 + fr;
  const int bRow = wc * 64 + fr;

  i32x4 acc[8][4] = {};

  // ---- prologue: stage U(0),U(1),U(2); keep newest 8 in flight ----
  stageA(0); stageB(0);
  if (NT > 1) { stageA(1); stageB(1); }
  if (NT > 2) { stageA(2); stageB(2); }
  if (NT > 2)      asm volatile("s_waitcnt vmcnt(8)" ::: "memory");
  else if (NT > 1) asm volatile("s_waitcnt vmcnt(4)" ::: "memory");
  else             asm volatile("s_waitcnt vmcnt(0)" ::: "memory");
  __builtin_amdgcn_s_barrier();
  __builtin_amdgcn_sched_barrier(0);

  for (int t = 0; t < NT; ++t) {
    const int8_t* sA = &lds[(t & 3) * SLOT_BYTES];
    const int8_t* sB = sA + 16384;
    i32x4 bfr[4], a0[4], a1[4];

    // ======== phase 0: B + A-low reads | stage(t+3) | 16 MFMA ========
#pragma unroll
    for (int j = 0; j < 4; ++j)
      bfr[j] = *(const i32x4*)&sB[(bRow + j * 16) * 64 + coff];
#pragma unroll
    for (int i = 0; i < 4; ++i)
      a0[i] = *(const i32x4*)&sA[(aRow + i * 16) * 64 + coff];
    if (t + 3 < NT) { stageA(t + 3); stageB(t + 3); }
    __builtin_amdgcn_s_barrier();
    asm volatile("s_waitcnt lgkmcnt(0)" ::: "memory");
    __builtin_amdgcn_sched_barrier(0);
    __builtin_amdgcn_s_setprio(1);
#pragma unroll
    for (int i = 0; i < 4; ++i)
#pragma unroll
      for (int j = 0; j < 4; ++j)
        acc[i][j] = __builtin_amdgcn_mfma_i32_16x16x64_i8(a0[i], bfr[j], acc[i][j], 0, 0, 0);
    __builtin_amdgcn_s_setprio(0);
    __builtin_amdgcn_s_barrier();

    // ======== phase 1: A-high reads | 16 MFMA | counted vmcnt ========
#pragma unroll
    for (int i = 0; i < 4; ++i)
      a1[i] = *(const i32x4*)&sA[(aRow + 64 + i * 16) * 64 + coff];
    __builtin_amdgcn_s_barrier();
    asm volatile("s_waitcnt lgkmcnt(0)" ::: "memory");
    __builtin_amdgcn_sched_barrier(0);
    __builtin_amdgcn_s_setprio(1);
#pragma unroll
    for (int i = 0; i < 4; ++i)
#pragma unroll
      for (int j = 0; j < 4; ++j)
        acc[4 + i][j] = __builtin_amdgcn_mfma_i32_16x16x64_i8(a1[i], bfr[j], acc[4 + i][j], 0, 0, 0);
    __builtin_amdgcn_s_setprio(0);
    if (t < NT - 1) {
      if (t + 3 < NT)       asm volatile("s_waitcnt vmcnt(8)" ::: "memory");
      else if (t + 3 == NT) asm volatile("s_waitcnt vmcnt(4)" ::: "memory");
      else                  asm volatile("s_waitcnt vmcnt(0)" ::: "memory");
      __builtin_amdgcn_s_barrier();
      __builtin_amdgcn_sched_barrier(0);
    }
  }

  // ---- epilogue: C/D col=lane&15, row=(lane>>4)*4+reg; j innermost ----
  const int r4 = (lane >> 4) << 2;
  const int cn0 = bn * BN + wc * 64 + fr;
  float aw4[4], zs4[4], bs4[4];
#pragma unroll
  for (int j = 0; j < 4; ++j) {
    aw4[j] = atwd[cn0 + j * 16];
    zs4[j] = zpws[cn0 + j * 16];
    bs4[j] = bias[cn0 + j * 16];
  }
#pragma unroll
  for (int mi = 0; mi < 8; ++mi) {
#pragma unroll
    for (int r = 0; r < 4; ++r) {
      const size_t rbase = (size_t)(bm * BM + wr * 128 + mi * 16 + r4 + r) * (size_t)Nc;
#pragma unroll
      for (int j = 0; j < 4; ++j) {
        float v = (float)acc[mi][j][r] * aw4[j] - zs4[j] + bs4[j];
        v = __half2float(__float2half(v));  // match fp16 output rounding
        out[rbase + cn0 + j * 16] = v;
      }
    }
  }
}

extern "C" void kernel_launch(void* const* d_in, const int* in_sizes, int n_in,
                              void* d_out, int out_size, void* d_ws, size_t ws_size,
                              hipStream_t stream) {
  const float* x         = (const float*)d_in[0];
  const float* act_delta = (const float*)d_in[1];
  const float* act_zp    = (const float*)d_in[2];
  const float* zpws      = (const float*)d_in[3];
  const float* atwd      = (const float*)d_in[4];
  const float* bias      = (const float*)d_in[5];
  const int*   w32       = (const int*)d_in[6];
  float* out = (float*)d_out;

  const int N = in_sizes[5];
  const int K = in_sizes[6] / N;
  const int M = in_sizes[0] / K;

  int8_t* q  = (int8_t*)d_ws;               // M*K bytes
  int8_t* wp = q + (size_t)M * K;           // N*K bytes

  {
    int n16 = (M * K) / 16;
    int grid = (n16 + 255) / 256;
    if (grid > 2048) grid = 2048;
    quant_x_kernel<<<grid, 256, 0, stream>>>(x, act_delta, act_zp, q, n16);
  }
  {
    int n16 = (N * K) / 16;
    pack_w_kernel<<<(n16 + 255) / 256, 256, 0, stream>>>(w32, wp, n16);
  }
  {
    dim3 grid((M / BM) * (N / BN));
    gemm_i8_kernel<<<grid, THREADS, 0, stream>>>(q, wp, atwd, zpws, bias, out, M, N, K);
  }
}